// Round 14
// baseline (338.101 us; speedup 1.0000x reference)
//
#include <hip/hip_runtime.h>

// OT_GNN_layer — round 14: full fusion (dots + Sinkhorn in one wave).
// N,F,T,Tn,C = 10000,128,16,8,8 ; E=160000 ; planar edge; hardcoded.
// R13: mh 145us (latency-bound, VALU floor ~35us) + sink 183us (issue-bound,
// VALUBusy 87%) + 87MB HBM bridge. Fusion: phase-1 dot accumulates straight
// into the sink lane layout (lane = (t, colpair p) owns v2f columns) via a
// pair-transposed TF table (tftp[c][pair=lane][k][2]) -> 4 pk_fma per
// (chunk,row), x splats free via op_sel from LDS-broadcast float4.
// Phase-2 = byte-identical validated R13 Sinkhorn (Mh stays in registers).

#define F_DIM 128
#define KN 16
#define NL 17
#define TT 16
#define TN 8
#define N_NODES 10000
#define E_EDGES 160000
#define CEXP 7.2134752044448170f    // (1/EPS)*log2(e), EPS=0.2
#define ICEXP 0.138629436111989062f // 1/CEXP

// ws float offsets
#define WS_TFSQ 0
#define WS_CC 128
#define WS_C2 256
#define WS_TFT 1280   // tftp: 32c x 64pair x 4k x 2 = 16384 floats

typedef float v2f __attribute__((ext_vector_type(2)));

template <int CTRL>
__device__ __forceinline__ float dppmov(float x) {
  return __int_as_float(__builtin_amdgcn_update_dpp(
      0, __float_as_int(x), CTRL, 0xF, 0xF, true));
}
__device__ __forceinline__ float q4sum(float x) {
  x += dppmov<0xB1>(x);
  x += dppmov<0x4E>(x);
  return x;
}
__device__ __forceinline__ float q4min(float x) {
  x = fminf(x, dppmov<0xB1>(x));
  x = fminf(x, dppmov<0x4E>(x));
  return x;
}
__device__ __forceinline__ v2f exp2v(v2f a) {
  v2f r; r.x = exp2f(a.x); r.y = exp2f(a.y); return r;
}
__device__ __forceinline__ v2f rcpv(v2f a) {
  v2f r;
  r.x = __builtin_amdgcn_rcpf(a.x);
  r.y = __builtin_amdgcn_rcpf(a.y);
  return r;
}
__device__ __forceinline__ v2f minv(v2f a, v2f b) {
  v2f r; r.x = fminf(a.x, b.x); r.y = fminf(a.y, b.y); return r;
}

// batched reciprocal of 17 positive values: 4 rcp + ~39 mul (validated R11)
__device__ __forceinline__ void minv17(const float r[NL], float U[NL]) {
  {
    float p1 = r[0] * r[1], p2 = p1 * r[2], p3 = p2 * r[3];
    float R = __builtin_amdgcn_rcpf(p3);
    U[3] = R * p2; R *= r[3];
    U[2] = R * p1; R *= r[2];
    U[1] = R * r[0];
    U[0] = R * r[1];
  }
  {
    float p1 = r[4] * r[5], p2 = p1 * r[6], p3 = p2 * r[7];
    float R = __builtin_amdgcn_rcpf(p3);
    U[7] = R * p2; R *= r[7];
    U[6] = R * p1; R *= r[6];
    U[5] = R * r[4];
    U[4] = R * r[5];
  }
  {
    float p1 = r[8] * r[9], p2 = p1 * r[10], p3 = p2 * r[11];
    float R = __builtin_amdgcn_rcpf(p3);
    U[11] = R * p2; R *= r[11];
    U[10] = R * p1; R *= r[10];
    U[9] = R * r[8];
    U[8] = R * r[9];
  }
  {
    float p1 = r[12] * r[13], p2 = p1 * r[14], p3 = p2 * r[15],
          p4 = p3 * r[16];
    float R = __builtin_amdgcn_rcpf(p4);
    U[16] = R * p3; R *= r[16];
    U[15] = R * p2; R *= r[15];
    U[14] = R * p1; R *= r[14];
    U[13] = R * r[12];
    U[12] = R * r[13];
  }
}

// ---------------- setup: tables + pair-transposed TF ----------------
__global__ __launch_bounds__(256) void setup_kernel(
    const float* __restrict__ L, const float* __restrict__ TF,
    float* __restrict__ ws) {
  const int tid = threadIdx.x;
  if (tid < 128) {
    const int t = tid >> 3, r = tid & 7;
    float q = 0.f;
#pragma unroll
    for (int mm = 0; mm < TN; ++mm) {
      float val = 0.5f * (L[t * 64 + r * 8 + mm] + L[t * 64 + mm * 8 + r]);
      ws[WS_C2 + t * 64 + r * 8 + mm] = val;
      q += val * val;
    }
    ws[WS_CC + tid] = 0.125f * q;
  } else {
    const int row = tid - 128;
    const float4* tf = (const float4*)(TF + (size_t)row * F_DIM);
    float s = 0.f;
#pragma unroll
    for (int c = 0; c < 32; ++c) {
      float4 v = tf[c];
      s += v.x * v.x + v.y * v.y + v.z * v.z + v.w * v.w;
    }
    ws[WS_TFSQ + row] = s;
  }
  // tftp[c*512 + pair*8 + k*2 + par] = TF[pair*2+par][c*4+k]
  for (int i = tid; i < 16384; i += 256) {
    int c = i >> 9, rem = i & 511;
    int pair = rem >> 3, k = (rem >> 1) & 3, par = i & 1;
    ws[WS_TFT + i] = TF[(size_t)(pair * 2 + par) * F_DIM + c * 4 + k];
  }
}

// ---------------- fused: dots -> Mh (regs) -> Sinkhorn -> head ----------------
__global__ __launch_bounds__(256) void fgw_fused_kernel(
    const float* __restrict__ x, const int* __restrict__ edge,
    const float* __restrict__ ws, const float* __restrict__ W,
    const float* __restrict__ bias, float* __restrict__ out) {
  __shared__ float xls[4][NL][132];
  __shared__ float xsqs[4][NL];
  __shared__ int nas[4][NL];
  __shared__ float C2s[TT * 68];
  __shared__ float sc[4][TT * 20];
  __shared__ float fgw_s[4][TT];

  const int tid = threadIdx.x;
  const int node0 = blockIdx.x * 4;
  const int* dst = edge + E_EDGES;

  for (int i = tid; i < 1024; i += 256) {
    int t = i >> 6, rest = i & 63;
    C2s[t * 68 + rest] = ws[WS_C2 + i];
  }
  if (tid < 4 * NL) {
    int nl = tid / NL, a = tid - nl * NL;
    int nd = node0 + nl;
    nas[nl][a] = (a == 0) ? nd : dst[nd * KN + a - 1];
  }
  __syncthreads();

  for (int i = tid; i < 4 * NL * 32; i += 256) {
    int nl = i / (NL * 32);
    int ii = i - nl * (NL * 32);
    int row = ii >> 5, c4 = ii & 31;
    float4 v = ((const float4*)(x + (size_t)nas[nl][row] * F_DIM))[c4];
    *(float4*)&xls[nl][row][c4 * 4] = v;
  }
  __syncthreads();

  if (tid < 4 * NL) {
    int nl = tid / NL, a = tid - nl * NL;
    v2f xq = {0.f, 0.f};
#pragma unroll
    for (int c = 0; c < 32; ++c) {
      float4 xv = *(const float4*)&xls[nl][a][c * 4];
      v2f xa = {xv.x, xv.y}, xb = {xv.z, xv.w};
      xq = xa * xa + xq;
      xq = xb * xb + xq;
    }
    xsqs[nl][a] = xq.x + xq.y;
  }
  __syncthreads();

  const int lane = tid & 63;
  const int w = tid >> 6;
  const int node = node0 + w;
  const int t = lane >> 2;   // template
  const int p = lane & 3;    // column pair: m = {2p, 2p+1}

  // ---- phase 1: d[a] = (dot(x_a, TF_col0), dot(x_a, TF_col1)) ----
  v2f d[NL];
#pragma unroll
  for (int a = 0; a < NL; ++a) d[a] = (v2f){0.f, 0.f};

  const float* tftp = ws + WS_TFT;
#pragma unroll 2
  for (int c = 0; c < 32; ++c) {
    float4 t0 = *(const float4*)(tftp + c * 512 + lane * 8);      // k0,k1
    float4 t1 = *(const float4*)(tftp + c * 512 + lane * 8 + 4);  // k2,k3
    v2f ta = {t0.x, t0.y}, tb = {t0.z, t0.w};
    v2f tc = {t1.x, t1.y}, td = {t1.z, t1.w};
#pragma unroll
    for (int a = 0; a < NL; ++a) {
      float4 xv = *(const float4*)&xls[w][a][c * 4];  // LDS broadcast
      d[a] += (v2f){xv.x, xv.x} * ta;
      d[a] += (v2f){xv.y, xv.y} * tb;
      d[a] += (v2f){xv.z, xv.z} * tc;
      d[a] += (v2f){xv.w, xv.w} * td;
    }
  }

  // ---- Mh (v2f, in regs) -> EM2 ----
  const v2f tfsq2 = *(const v2f*)(ws + WS_TFSQ + 2 * lane);
  const v2f cc2 = *(const v2f*)(ws + WS_CC + 2 * lane);
  const v2f b0 = 0.5f * ((v2f){16.f / 17.f, 16.f / 17.f} + cc2);
  const v2f ba = 0.5f * ((v2f){1.f / 17.f, 1.f / 17.f} + cc2);

  v2f EM2[NL], Mh02, mnr;
  {
    v2f m0 = (xsqs[w][0] + tfsq2 - 2.f * d[0]) * (1.f / 256.f) + b0;
    Mh02 = m0;
    EM2[0] = exp2v(-m0 * CEXP);
    v2f m1 = (xsqs[w][1] + tfsq2 - 2.f * d[1]) * (1.f / 256.f) + ba;
    mnr = m1;
    EM2[1] = exp2v(-m1 * CEXP);
#pragma unroll
    for (int a = 2; a < NL; ++a) {
      v2f mv = (xsqs[w][a] + tfsq2 - 2.f * d[a]) * (1.f / 256.f) + ba;
      mnr = minv(mnr, mv);
      EM2[a] = exp2v(-mv * CEXP);
    }
  }

  // ---- phase 2: Sinkhorn (byte-identical to validated R13) ----
  v2f PK2[NL];
#pragma unroll
  for (int a = 0; a < NL; ++a) PK2[a] = (v2f){1.f / 136.f, 1.f / 136.f};

  float r[NL], U[NL];
  float* myc = &sc[w][t * 20];
  v2f A02, A12;

#pragma unroll 1
  for (int it = 0; it < 5; ++it) {
    v2f sP2 = PK2[1];
#pragma unroll
    for (int a = 2; a < NL; ++a) sP2 += PK2[a];
    *(v2f*)&myc[2 * p] = sP2;
    *(v2f*)&myc[8 + 2 * p] = PK2[0];
    float4 s01 = *(const float4*)&myc[0];
    float4 s23 = *(const float4*)&myc[4];
    float4 p01 = *(const float4*)&myc[8];
    float4 p23 = *(const float4*)&myc[12];
    {
      const float* c2b = &C2s[t * 68 + 2 * p];
      v2f c0 = *(const v2f*)(c2b), c1 = *(const v2f*)(c2b + 8),
          c2 = *(const v2f*)(c2b + 16), c3 = *(const v2f*)(c2b + 24),
          c4 = *(const v2f*)(c2b + 32), c5 = *(const v2f*)(c2b + 40),
          c6 = *(const v2f*)(c2b + 48), c7 = *(const v2f*)(c2b + 56);
      A02 = c0 * s01.x + c1 * s01.y;
      A02 += c2 * s01.z + c3 * s01.w;
      A02 += c4 * s23.x + c5 * s23.y;
      A02 += c6 * s23.z + c7 * s23.w;
      A12 = c0 * p01.x + c1 * p01.y;
      A12 += c2 * p01.z + c3 * p01.w;
      A12 += c4 * p23.x + c5 * p23.y;
      A12 += c6 * p23.z + c7 * p23.w;
    }

    v2f g0 = Mh02 - A02, g1 = mnr - A12;
    float gmin = fminf(fminf(g0.x, g0.y), fminf(g1.x, g1.y));
    gmin = q4min(gmin);

    v2f EA0 = exp2v((A02 + gmin) * CEXP);
    v2f EA1 = exp2v((A12 + gmin) * CEXP);
    PK2[0] = PK2[0] * EM2[0] * EA0;
#pragma unroll
    for (int a = 1; a < NL; ++a) PK2[a] = PK2[a] * EM2[a] * EA1;

    v2f V;
    {
#pragma unroll
      for (int a = 0; a < NL; ++a) {
        float rr = PK2[a].x + PK2[a].y;
        r[a] = q4sum(rr);
      }
      minv17(r, U);
      v2f s2 = PK2[0] * U[0];
#pragma unroll
      for (int a = 1; a < NL; ++a) s2 += PK2[a] * U[a];
      V = 2.125f * rcpv(s2);
    }
#pragma unroll 1
    for (int si = 1; si < 10; ++si) {
#pragma unroll
      for (int a = 0; a < NL; ++a) {
        v2f pr = PK2[a] * V;
        r[a] = q4sum(pr.x + pr.y);
      }
      minv17(r, U);
      v2f s2 = PK2[0] * U[0];
#pragma unroll
      for (int a = 1; a < NL; ++a) s2 += PK2[a] * U[a];
      V = 2.125f * rcpv(s2);
    }
    const v2f hV = V * (1.f / 17.f);
#pragma unroll
    for (int a = 0; a < NL; ++a) PK2[a] = PK2[a] * U[a] * hV;
  }

  // ---- final fgw ----
  {
    v2f sP2 = PK2[1];
#pragma unroll
    for (int a = 2; a < NL; ++a) sP2 += PK2[a];
    *(v2f*)&myc[2 * p] = sP2;
    *(v2f*)&myc[8 + 2 * p] = PK2[0];
    float4 s01 = *(const float4*)&myc[0];
    float4 s23 = *(const float4*)&myc[4];
    float4 p01 = *(const float4*)&myc[8];
    float4 p23 = *(const float4*)&myc[12];
    const float* c2b = &C2s[t * 68 + 2 * p];
    v2f c0 = *(const v2f*)(c2b), c1 = *(const v2f*)(c2b + 8),
        c2 = *(const v2f*)(c2b + 16), c3 = *(const v2f*)(c2b + 24),
        c4 = *(const v2f*)(c2b + 32), c5 = *(const v2f*)(c2b + 40),
        c6 = *(const v2f*)(c2b + 48), c7 = *(const v2f*)(c2b + 56);
    A02 = c0 * s01.x + c1 * s01.y;
    A02 += c2 * s01.z + c3 * s01.w;
    A02 += c4 * s23.x + c5 * s23.y;
    A02 += c6 * s23.z + c7 * s23.w;
    A12 = c0 * p01.x + c1 * p01.y;
    A12 += c2 * p01.z + c3 * p01.w;
    A12 += c4 * p23.x + c5 * p23.y;
    A12 += c6 * p23.z + c7 * p23.w;
  }
  v2f acc2 = {0.f, 0.f};
#pragma unroll
  for (int a = 0; a < NL; ++a) {
    v2f mh2;
    mh2.x = -__log2f(EM2[a].x) * ICEXP;
    mh2.y = -__log2f(EM2[a].y) * ICEXP;
    acc2 += (mh2 - ((a == 0) ? A02 : A12)) * PK2[a];
  }
  float acc = q4sum(acc2.x + acc2.y);  // fgw(node,t), replicated in quad

  if (p == 0) fgw_s[w][t] = acc;
  // intra-wave LDS RAW: compiler orders with lgkmcnt (validated R13)
  if (lane < 8) {
    float o = bias[lane];
#pragma unroll
    for (int t2 = 0; t2 < TT; ++t2) o += fgw_s[w][t2] * W[t2 * 8 + lane];
    out[node * 8 + lane] = o;
  }
}

extern "C" void kernel_launch(void* const* d_in, const int* in_sizes, int n_in,
                              void* d_out, int out_size, void* d_ws, size_t ws_size,
                              hipStream_t stream) {
  const float* x = (const float*)d_in[0];
  const int* edge = (const int*)d_in[1];
  const float* L = (const float*)d_in[2];
  const float* TF = (const float*)d_in[3];
  const float* W = (const float*)d_in[4];
  const float* bias = (const float*)d_in[5];
  float* out = (float*)d_out;
  float* ws = (float*)d_ws;
  (void)in_sizes; (void)n_in; (void)ws_size; (void)out_size;

  setup_kernel<<<1, 256, 0, stream>>>(L, TF, ws);
  fgw_fused_kernel<<<N_NODES / 4, 256, 0, stream>>>(x, edge, ws, W, bias,
                                                    out);
}